// Round 1
// baseline (4026.125 us; speedup 1.0000x reference)
//
#include <hip/hip_runtime.h>
#include <stdint.h>

#define NTOT   12288
#define NCH    6
#define NCHUNK 12
#define CSZ    1024
#define CW     16          // CSZ/64 words per suppression row
#define NBATCH 16          // 64-box batches per chunk
#define CONF_THR 0.01f
#define NMS_THR  0.45f

typedef unsigned long long u64;
typedef uint32_t u32;

__device__ __forceinline__ float sigmf(float x){ return 1.0f/(1.0f+expf(-x)); }

// exact reference IoU-suppression test: inter = prod(br-tl) * all(tl<br); iou = inter/(ai+aj-inter)
__device__ __forceinline__ bool sup_pair(float ax1,float ay1,float ax2,float ay2,float aar,
                                         float bx1,float by1,float bx2,float by2,float bar){
  float tlx=fmaxf(ax1,bx1), tly=fmaxf(ay1,by1);
  float brx=fminf(ax2,bx2), bry=fminf(ay2,by2);
  float inter=(brx-tlx)*(bry-tly);
  if(!(tlx<brx && tly<bry)) inter=0.0f;
  float iou = inter/((aar+bar)-inter);
  return iou >= NMS_THR;
}

// ---------------- decode ----------------
__global__ void k_decode(const float* __restrict__ feat, const float* __restrict__ anchors,
                         float* ox1,float* oy1,float* ox2,float* oy2,
                         float* oobj,float* ocls,float* oscore,u32* okey){
  int n = blockIdx.x*256 + threadIdx.x;
  if(n>=NTOT) return;
  int a = n >> 12;
  int cell = n & 4095;
  int gy = cell >> 6, gx = cell & 63;
  const float* f = feat + a*NCH*4096 + cell;
  float v0=f[0], v1=f[4096], v2=f[8192], v3=f[12288], v4=f[16384], v5=f[20480];
  float aw = anchors[2*a]   * 0.125f;   // /8 exact
  float ah = anchors[2*a+1] * 0.125f;
  float px = (sigmf(v0) + (float)gx) * 8.0f;
  float py = (sigmf(v1) + (float)gy) * 8.0f;
  float pw = (expf(v2)*aw) * 8.0f;
  float ph = (expf(v3)*ah) * 8.0f;
  float obj = sigmf(v4), cls = sigmf(v5);
  float x1 = px - pw*0.5f, y1 = py - ph*0.5f;
  float x2 = px + pw*0.5f, y2 = py + ph*0.5f;
  float sc = obj*cls;
  ox1[n]=x1; oy1[n]=y1; ox2[n]=x2; oy2[n]=y2;
  oobj[n]=obj; ocls[n]=cls; oscore[n]=sc;
  u32 u = __float_as_uint(sc);
  u32 asc = (u & 0x80000000u) ? ~u : (u | 0x80000000u); // ascending-order uint map
  okey[n] = ~asc;                                       // descending: higher score -> smaller key
}

// ---------------- stable rank sort (brute-force counting) + scatter to sorted arrays ----------------
__global__ void k_rank(const u32* __restrict__ okey,
                       const float* __restrict__ ox1,const float* __restrict__ oy1,
                       const float* __restrict__ ox2,const float* __restrict__ oy2,
                       const float* __restrict__ oobj,const float* __restrict__ ocls,
                       const float* __restrict__ oscore,
                       int* order,float* sx1,float* sy1,float* sx2,float* sy2,
                       float* sarea,float* sobj,float* scls,u32* presup,u32* keep){
  __shared__ u32 tile[2048];
  int n = blockIdx.x*256 + threadIdx.x;
  u32 my = okey[n];
  int rank = 0;
  for(int t=0;t<NTOT;t+=2048){
    __syncthreads();
    for(int k=threadIdx.x;k<2048;k+=256) tile[k]=okey[t+k];
    __syncthreads();
    #pragma unroll 8
    for(int k=0;k<2048;k++){
      u32 kj = tile[k];
      int j = t+k;
      rank += (int)((kj < my) || (kj==my && j<n));   // stable tie-break = jnp stable argsort
    }
  }
  order[rank]=n;
  float x1=ox1[n], y1=oy1[n], x2=ox2[n], y2=oy2[n];
  sx1[rank]=x1; sy1[rank]=y1; sx2[rank]=x2; sy2[rank]=y2;
  sarea[rank]=(x2-x1)*(y2-y1);
  sobj[rank]=oobj[n]; scls[rank]=ocls[n];
  presup[rank] = (oscore[n] >= CONF_THR) ? 0u : 1u;  // invalid boxes start "suppressed"
  keep[rank]=0u;
}

// ---------------- intra-chunk suppression rows: bit j set if gi suppresses gj (gj>gi, same chunk) ----------------
__global__ void k_rows(const float* __restrict__ sx1,const float* __restrict__ sy1,
                       const float* __restrict__ sx2,const float* __restrict__ sy2,
                       const float* __restrict__ sarea,u64* __restrict__ rows){
  int id = blockIdx.x*256+threadIdx.x;
  if(id >= NTOT*CW) return;
  int w  = id & (CW-1);
  int gi = id >> 4;
  int c  = gi >> 10;          // /CSZ
  float ax1=sx1[gi],ay1=sy1[gi],ax2=sx2[gi],ay2=sy2[gi],aar=sarea[gi];
  int jbase = c*CSZ + w*64;
  u64 bits=0;
  for(int b=0;b<64;b++){
    int gj=jbase+b;
    if(gj>gi){
      if(sup_pair(ax1,ay1,ax2,ay2,aar, sx1[gj],sy1[gj],sx2[gj],sy2[gj],sarea[gj]))
        bits |= (1ull<<(unsigned)b);
    }
  }
  rows[id]=bits;
}

// ---------------- intra-64-batch column masks: bit i set if batch-member i (<j) suppresses j ----------------
__global__ void k_colmask(const float* __restrict__ sx1,const float* __restrict__ sy1,
                          const float* __restrict__ sx2,const float* __restrict__ sy2,
                          const float* __restrict__ sarea,u64* __restrict__ colmask){
  int j = blockIdx.x*256+threadIdx.x;
  if(j>=NTOT) return;
  int jl = j & 63, base = j & ~63;
  float bx1=sx1[j],by1=sy1[j],bx2=sx2[j],by2=sy2[j],bar=sarea[j];
  u64 bits=0;
  for(int i=0;i<jl;i++){
    int gi=base+i;
    if(sup_pair(sx1[gi],sy1[gi],sx2[gi],sy2[gi],sarea[gi],bx1,by1,bx2,by2,bar))
      bits |= (1ull<<(unsigned)i);
  }
  colmask[j]=bits;
}

// ---------------- serial greedy resolve of one chunk (single wave) ----------------
__global__ __launch_bounds__(64) void k_resolve(const u64* __restrict__ rows,
                          const u64* __restrict__ colmask,
                          const u32* __restrict__ presup,
                          u32* __restrict__ keep, int chunk){
  __shared__ u64 lrow[64*CW];
  __shared__ int tlist[64];
  __shared__ int s_kc;
  int lane = threadIdx.x;
  u64 supW = 0;                    // lanes 0..CW-1 hold chunk-local suppressed-bit words
  int cbase = chunk*CSZ;
  for(int b=0;b<NBATCH;b++){
    int ibase = cbase + b*64;
    u32 pre = presup[ibase+lane];
    u64 col = colmask[ibase+lane];
    u32 lo = __shfl((u32)(supW & 0xffffffffull), b);
    u32 hi = __shfl((u32)(supW >> 32), b);
    u64 supb = ((u64)hi<<32) | lo;
    u64 cand = __ballot(pre==0u) & ~supb;
    u64 keep64 = 0;
    while(cand){                                  // uniform loop, one iter per kept box
      int t = __builtin_ctzll(cand);
      keep64 |= (1ull<<(unsigned)t);
      u64 died = __ballot(((col>>(unsigned)t)&1ull)!=0ull);
      cand &= ~died;
      cand &= ~(1ull<<(unsigned)t);
    }
    keep[ibase+lane] = (u32)((keep64>>(unsigned)lane)&1ull);
    if(lane==0){
      int kc=0; u64 kk=keep64;
      while(kk){ tlist[kc++]=__builtin_ctzll(kk); kk &= kk-1ull; }
      s_kc=kc;
    }
    __syncthreads();
    int kc=s_kc;
    for(int idx=lane; idx<kc*CW; idx+=64){        // cooperative gather of kept rows
      int r=idx>>4, l=idx&(CW-1);
      lrow[idx] = rows[(u64)(ibase+tlist[r])*CW + (u64)l];
    }
    __syncthreads();
    if(lane<CW){
      u64 acc=0;
      for(int r=0;r<kc;r++) acc |= lrow[r*CW+lane];
      supW |= acc;
    }
    __syncthreads();
  }
}

// ---------------- apply chunk's kept boxes to all later boxes ----------------
__global__ void k_forward(const float* __restrict__ sx1,const float* __restrict__ sy1,
                          const float* __restrict__ sx2,const float* __restrict__ sy2,
                          const float* __restrict__ sarea,
                          const u32* __restrict__ keep,
                          u32* __restrict__ presup,int chunk){
  __shared__ float kx1[CSZ],ky1[CSZ],kx2[CSZ],ky2[CSZ],kar[CSZ];
  __shared__ int s_cnt;
  if(threadIdx.x==0) s_cnt=0;
  __syncthreads();
  int cbase=chunk*CSZ;
  for(int i=threadIdx.x;i<CSZ;i+=256){
    if(keep[cbase+i]){
      int p=atomicAdd(&s_cnt,1);
      kx1[p]=sx1[cbase+i]; ky1[p]=sy1[cbase+i];
      kx2[p]=sx2[cbase+i]; ky2[p]=sy2[cbase+i];
      kar[p]=sarea[cbase+i];
    }
  }
  __syncthreads();
  int kc=s_cnt;
  int jstart=cbase+CSZ;
  for(int j=jstart + (int)blockIdx.x*256 + (int)threadIdx.x; j<NTOT; j+=(int)gridDim.x*256){
    if(presup[j]) continue;
    float bx1=sx1[j],by1=sy1[j],bx2=sx2[j],by2=sy2[j],bar=sarea[j];
    bool s=false;
    for(int r=0;r<kc;r++){
      if(sup_pair(kx1[r],ky1[r],kx2[r],ky2[r],kar[r],bx1,by1,bx2,by2,bar)){ s=true; break; }
    }
    if(s) presup[j]=1u;
  }
}

// ---------------- write det (original order) and keep flags ----------------
__global__ void k_final(const int* __restrict__ order,const u32* __restrict__ keep,
                        const float* __restrict__ sx1,const float* __restrict__ sy1,
                        const float* __restrict__ sx2,const float* __restrict__ sy2,
                        const float* __restrict__ sobj,const float* __restrict__ scls,
                        float* __restrict__ out){
  int i=blockIdx.x*256+threadIdx.x;
  if(i>=NTOT) return;
  int n=order[i];
  float kf = keep[i] ? 1.0f : 0.0f;
  float* det = out + (size_t)n*6;
  det[0]=sx1[i]*kf; det[1]=sy1[i]*kf; det[2]=sx2[i]*kf; det[3]=sy2[i]*kf;
  det[4]=sobj[i]*kf; det[5]=scls[i]*kf;
  out[NTOT*6 + n] = kf;
}

extern "C" void kernel_launch(void* const* d_in,const int* in_sizes,int n_in,
                              void* d_out,int out_size,void* d_ws,size_t ws_size,
                              hipStream_t stream){
  const float* feat=(const float*)d_in[0];
  const float* anchors=(const float*)d_in[1];
  float* out=(float*)d_out;

  char* w=(char*)d_ws;
  auto alloc=[&](size_t bytes)->char*{ char* p=w; w += (bytes+255)&~255ull; return p; };
  float *ox1=(float*)alloc(NTOT*4), *oy1=(float*)alloc(NTOT*4);
  float *ox2=(float*)alloc(NTOT*4), *oy2=(float*)alloc(NTOT*4);
  float *oobj=(float*)alloc(NTOT*4), *ocls=(float*)alloc(NTOT*4), *oscore=(float*)alloc(NTOT*4);
  u32   *okey=(u32*)alloc(NTOT*4);
  float *sx1=(float*)alloc(NTOT*4), *sy1=(float*)alloc(NTOT*4);
  float *sx2=(float*)alloc(NTOT*4), *sy2=(float*)alloc(NTOT*4);
  float *sarea=(float*)alloc(NTOT*4), *sobj=(float*)alloc(NTOT*4), *scls=(float*)alloc(NTOT*4);
  int   *order=(int*)alloc(NTOT*4);
  u32   *keep=(u32*)alloc(NTOT*4), *presup=(u32*)alloc(NTOT*4);
  u64   *colmask=(u64*)alloc(NTOT*8);
  u64   *rows=(u64*)alloc((size_t)NTOT*CW*8);

  hipLaunchKernelGGL(k_decode, dim3(NTOT/256),dim3(256),0,stream,
                     feat,anchors,ox1,oy1,ox2,oy2,oobj,ocls,oscore,okey);
  hipLaunchKernelGGL(k_rank, dim3(NTOT/256),dim3(256),0,stream,
                     okey,ox1,oy1,ox2,oy2,oobj,ocls,oscore,
                     order,sx1,sy1,sx2,sy2,sarea,sobj,scls,presup,keep);
  hipLaunchKernelGGL(k_rows, dim3(NTOT*CW/256),dim3(256),0,stream,
                     sx1,sy1,sx2,sy2,sarea,rows);
  hipLaunchKernelGGL(k_colmask, dim3(NTOT/256),dim3(256),0,stream,
                     sx1,sy1,sx2,sy2,sarea,colmask);
  for(int c=0;c<NCHUNK;c++){
    hipLaunchKernelGGL(k_resolve, dim3(1),dim3(64),0,stream, rows,colmask,presup,keep,c);
    if(c+1<NCHUNK)
      hipLaunchKernelGGL(k_forward, dim3(44),dim3(256),0,stream,
                         sx1,sy1,sx2,sy2,sarea,keep,presup,c);
  }
  hipLaunchKernelGGL(k_final, dim3(NTOT/256),dim3(256),0,stream,
                     order,keep,sx1,sy1,sx2,sy2,sobj,scls,out);
}

// Round 2
// 1533.517 us; speedup vs baseline: 2.6254x; 2.6254x over previous
//
#include <hip/hip_runtime.h>
#include <stdint.h>

#define NTOT   12288
#define NW     192           // NTOT/64 suppression-mask words
#define NCH    6
#define CONF_THR 0.01f
#define NMS_THR  0.45f

typedef unsigned long long u64;
typedef uint32_t u32;

__device__ __forceinline__ float sigmf(float x){ return 1.0f/(1.0f+expf(-x)); }

// exact reference IoU-suppression test
__device__ __forceinline__ bool sup_pair(float ax1,float ay1,float ax2,float ay2,float aar,
                                         float bx1,float by1,float bx2,float by2,float bar){
  float tlx=fmaxf(ax1,bx1), tly=fmaxf(ay1,by1);
  float brx=fminf(ax2,bx2), bry=fminf(ay2,by2);
  float inter=(brx-tlx)*(bry-tly);
  if(!(tlx<brx && tly<bry)) inter=0.0f;
  float iou = inter/((aar+bar)-inter);
  return iou >= NMS_THR;
}

__device__ __forceinline__ u64 rdlane64(u64 v, int src){
  u32 lo = (u32)__builtin_amdgcn_readlane((int)(u32)(v & 0xffffffffull), src);
  u32 hi = (u32)__builtin_amdgcn_readlane((int)(u32)(v>>32), src);
  return (((u64)hi)<<32) | (u64)lo;
}

// ---------------- decode ----------------
__global__ void k_decode(const float* __restrict__ feat, const float* __restrict__ anchors,
                         float4* __restrict__ obox, float* __restrict__ oobj,
                         float* __restrict__ ocls, float* __restrict__ oscore,
                         u32* __restrict__ okey, int* __restrict__ rank){
  int n = blockIdx.x*256 + threadIdx.x;
  int a = n >> 12;
  int cell = n & 4095;
  int gy = cell >> 6, gx = cell & 63;
  const float* f = feat + a*NCH*4096 + cell;
  float v0=f[0], v1=f[4096], v2=f[8192], v3=f[12288], v4=f[16384], v5=f[20480];
  float aw = anchors[2*a]   * 0.125f;
  float ah = anchors[2*a+1] * 0.125f;
  float px = (sigmf(v0) + (float)gx) * 8.0f;
  float py = (sigmf(v1) + (float)gy) * 8.0f;
  float pw = (expf(v2)*aw) * 8.0f;
  float ph = (expf(v3)*ah) * 8.0f;
  float obj = sigmf(v4), cls = sigmf(v5);
  float4 b;
  b.x = px - pw*0.5f; b.y = py - ph*0.5f;
  b.z = px + pw*0.5f; b.w = py + ph*0.5f;
  float sc = obj*cls;
  obox[n]=b; oobj[n]=obj; ocls[n]=cls; oscore[n]=sc;
  u32 u = __float_as_uint(sc);
  u32 asc = (u & 0x80000000u) ? ~u : (u | 0x80000000u);
  okey[n] = ~asc;            // descending: higher score -> smaller key
  rank[n] = 0;
}

// ---------------- partial rank over a 1024-key slice ----------------
__global__ __launch_bounds__(256) void k_rank_part(const u32* __restrict__ okey,
                                                   int* __restrict__ rank){
  __shared__ u32 tile[1024];
  int n = blockIdx.x*256 + threadIdx.x;
  int t0 = blockIdx.y * 1024;
  u32 my = okey[n];
  for(int k=threadIdx.x;k<1024;k+=256) tile[k]=okey[t0+k];
  __syncthreads();
  int r0=0,r1=0,r2=0,r3=0;
  #pragma unroll 4
  for(int k=0;k<1024;k+=4){
    uint4 kj = *reinterpret_cast<const uint4*>(&tile[k]);
    int j = t0+k;
    r0 += (int)((kj.x<my)||(kj.x==my && (j  )<n));
    r1 += (int)((kj.y<my)||(kj.y==my && (j+1)<n));
    r2 += (int)((kj.z<my)||(kj.z==my && (j+2)<n));
    r3 += (int)((kj.w<my)||(kj.w==my && (j+3)<n));
  }
  atomicAdd(&rank[n], r0+r1+r2+r3);
}

// ---------------- scatter into sorted arrays ----------------
__global__ void k_scatter(const int* __restrict__ rank,
                          const float4* __restrict__ obox,const float* __restrict__ oobj,
                          const float* __restrict__ ocls,const float* __restrict__ oscore,
                          float4* __restrict__ sbox,float* __restrict__ sarea,
                          float* __restrict__ sobj,float* __restrict__ scls,
                          u32* __restrict__ svalid,int* __restrict__ order){
  int n = blockIdx.x*256 + threadIdx.x;
  int r = rank[n];
  float4 b = obox[n];
  sbox[r]=b;
  sarea[r]=(b.z-b.x)*(b.w-b.y);
  sobj[r]=oobj[n]; scls[r]=ocls[n];
  svalid[r] = (oscore[n] >= CONF_THR) ? 1u : 0u;
  order[r]=n;
}

// ---------------- intra-word column masks + valid words ----------------
__global__ __launch_bounds__(256) void k_cmv(const float4* __restrict__ sbox,
                       const float* __restrict__ sarea,const u32* __restrict__ svalid,
                       u64* __restrict__ colmask,u64* __restrict__ validw){
  __shared__ float4 bb[256];
  __shared__ float  ar[256];
  int j = blockIdx.x*256 + threadIdx.x;
  int lane = threadIdx.x & 63;
  float4 b = sbox[j];
  float bar_ = sarea[j];
  bb[threadIdx.x]=b; ar[threadIdx.x]=bar_;
  __syncthreads();
  int base = threadIdx.x & ~63;
  u64 bits=0;
  for(int t=0;t<lane;t++){
    float4 a = bb[base+t];
    if(sup_pair(a.x,a.y,a.z,a.w,ar[base+t], b.x,b.y,b.z,b.w,bar_))
      bits |= (1ull<<(unsigned)t);
  }
  colmask[j]=bits;
  u64 vb = __ballot(svalid[j]!=0u);
  if(lane==0) validw[j>>6]=vb;
}

// ---------------- full suppression bitmap: one wave per row ----------------
__global__ __launch_bounds__(256) void k_rows(const float4* __restrict__ sbox,
                       const float* __restrict__ sarea,u64* __restrict__ rows){
  int i   = (blockIdx.x*256 + threadIdx.x) >> 6;   // row index = wave id
  int lane = threadIdx.x & 63;
  float4 a = sbox[i];
  float aar = sarea[i];
  int w0 = i >> 6;
  u64 r0=0,r1=0,r2=0;
  for(int w=w0; w<NW; ++w){
    int j = (w<<6) | lane;
    float4 b = sbox[j];
    bool s = (j>i) && sup_pair(a.x,a.y,a.z,a.w,aar, b.x,b.y,b.z,b.w,sarea[j]);
    u64 word = __ballot(s);
    if(lane == (w&63)){
      int sl = w>>6;
      if(sl==0) r0=word; else if(sl==1) r1=word; else r2=word;
    }
  }
  u64* rowp = rows + (size_t)i*NW;
  if(lane      >= w0) rowp[lane]      = r0;
  if(64+lane   >= w0) rowp[64+lane]   = r1;
  if(128+lane  >= w0) rowp[128+lane]  = r2;
}

// ---------------- single-wave greedy scan over the full bitmap ----------------
__global__ __launch_bounds__(64) void k_scan(const u64* __restrict__ rows,
                       const u64* __restrict__ colmask,const u64* __restrict__ validw,
                       u64* __restrict__ keepw){
  int lane = threadIdx.x;
  u64 m0=0,m1=0,m2=0;           // suppressed-mask words lane, 64+lane, 128+lane
  u64 k0=0,k1=0,k2=0;           // keep words
  u64 v0=validw[lane], v1=validw[64+lane], v2=validw[128+lane];
  u64 col = colmask[lane];      // colmask for word 0
  for(int w=0; w<NW; ++w){
    int src = w & 63, slot = w >> 6;
    u64 msel = (slot==0)?m0:((slot==1)?m1:m2);
    u64 vsel = (slot==0)?v0:((slot==1)?v1:v2);
    u64 supw = rdlane64(msel, src);
    u64 vw   = rdlane64(vsel, src);
    u64 colv = col;
    if(w+1<NW) col = colmask[((w+1)<<6) + lane];   // prefetch next word's colmask
    u64 cand = vw & ~supw;
    u64 keep64 = 0;
    {
      u64 c = cand;
      while(c){                                    // greedy within word (SALU, uniform)
        int t = __builtin_ctzll(c);
        keep64 |= (1ull<<(unsigned)t);
        c &= ~(1ull<<(unsigned)t);
        u64 died = __ballot(((colv>>(unsigned)t)&1ull)!=0ull);
        c &= ~died;
      }
    }
    if(lane==src){ if(slot==0)k0=keep64; else if(slot==1)k1=keep64; else k2=keep64; }
    // deferred OR of kept rows into mask (future words); 16-row rounds for load ILP
    u64 kk = keep64;
    const u64* rbase = rows + ((size_t)(w<<6))*NW;
    while(kk){
      int ts[16];
      #pragma unroll
      for(int s=0;s<16;s++){
        if(kk){ ts[s]=__builtin_ctzll(kk); kk &= kk-1ull; } else ts[s]=-1;
      }
      u64 ga[16],gb[16],gc[16];
      #pragma unroll
      for(int s=0;s<16;s++){
        if(ts[s]>=0){
          const u64* rp = rbase + (size_t)ts[s]*NW;
          ga[s]=rp[lane]; gb[s]=rp[64+lane]; gc[s]=rp[128+lane];
        } else { ga[s]=0; gb[s]=0; gc[s]=0; }
      }
      #pragma unroll
      for(int s=0;s<16;s++){ m0|=ga[s]; m1|=gb[s]; m2|=gc[s]; }
    }
  }
  keepw[lane]=k0; keepw[64+lane]=k1; keepw[128+lane]=k2;
}

// ---------------- final output ----------------
__global__ void k_final(const int* __restrict__ order,const u64* __restrict__ keepw,
                        const float4* __restrict__ sbox,const float* __restrict__ sobj,
                        const float* __restrict__ scls,float* __restrict__ out){
  int i = blockIdx.x*256 + threadIdx.x;
  int n = order[i];
  u64 kw = keepw[i>>6];
  float kf = ((kw>>(unsigned)(i&63))&1ull) ? 1.0f : 0.0f;
  float4 b = sbox[i];
  float* det = out + (size_t)n*6;
  det[0]=b.x*kf; det[1]=b.y*kf; det[2]=b.z*kf; det[3]=b.w*kf;
  det[4]=sobj[i]*kf; det[5]=scls[i]*kf;
  out[NTOT*6 + n] = kf;
}

extern "C" void kernel_launch(void* const* d_in,const int* in_sizes,int n_in,
                              void* d_out,int out_size,void* d_ws,size_t ws_size,
                              hipStream_t stream){
  const float* feat=(const float*)d_in[0];
  const float* anchors=(const float*)d_in[1];
  float* out=(float*)d_out;

  char* w=(char*)d_ws;
  auto alloc=[&](size_t bytes)->char*{ char* p=w; w += (bytes+255)&~255ull; return p; };
  float4 *obox =(float4*)alloc(NTOT*16);
  float  *oobj =(float*) alloc(NTOT*4);
  float  *ocls =(float*) alloc(NTOT*4);
  float  *oscore=(float*)alloc(NTOT*4);
  u32    *okey =(u32*)   alloc(NTOT*4);
  int    *rank =(int*)   alloc(NTOT*4);
  float4 *sbox =(float4*)alloc(NTOT*16);
  float  *sarea=(float*) alloc(NTOT*4);
  float  *sobj =(float*) alloc(NTOT*4);
  float  *scls =(float*) alloc(NTOT*4);
  u32    *svalid=(u32*)  alloc(NTOT*4);
  int    *order=(int*)   alloc(NTOT*4);
  u64    *colmask=(u64*) alloc(NTOT*8);
  u64    *validw =(u64*) alloc(NW*8);
  u64    *keepw  =(u64*) alloc(NW*8);
  u64    *rows   =(u64*) alloc((size_t)NTOT*NW*8);   // 18.9 MB

  hipLaunchKernelGGL(k_decode, dim3(NTOT/256),dim3(256),0,stream,
                     feat,anchors,obox,oobj,ocls,oscore,okey,rank);
  hipLaunchKernelGGL(k_rank_part, dim3(NTOT/256,12),dim3(256),0,stream, okey,rank);
  hipLaunchKernelGGL(k_scatter, dim3(NTOT/256),dim3(256),0,stream,
                     rank,obox,oobj,ocls,oscore,sbox,sarea,sobj,scls,svalid,order);
  hipLaunchKernelGGL(k_cmv, dim3(NTOT/256),dim3(256),0,stream,
                     sbox,sarea,svalid,colmask,validw);
  hipLaunchKernelGGL(k_rows, dim3(NTOT/4),dim3(256),0,stream, sbox,sarea,rows);
  hipLaunchKernelGGL(k_scan, dim3(1),dim3(64),0,stream, rows,colmask,validw,keepw);
  hipLaunchKernelGGL(k_final, dim3(NTOT/256),dim3(256),0,stream,
                     order,keepw,sbox,sobj,scls,out);
}

// Round 3
// 880.843 us; speedup vs baseline: 4.5708x; 1.7410x over previous
//
#include <hip/hip_runtime.h>
#include <stdint.h>

#define NTOT   12288
#define NW     192           // NTOT/64 suppression-mask words
#define NCH    6
#define SPW    32            // uint4 slots per sparse row (1 header + 31 entries)
#define CONF_THR 0.01f
#define NMS_THR  0.45f

typedef unsigned long long u64;
typedef uint32_t u32;

__device__ __forceinline__ float sigmf(float x){ return 1.0f/(1.0f+expf(-x)); }

// exact reference IoU-suppression test
__device__ __forceinline__ bool sup_pair(float ax1,float ay1,float ax2,float ay2,float aar,
                                         float bx1,float by1,float bx2,float by2,float bar){
  float tlx=fmaxf(ax1,bx1), tly=fmaxf(ay1,by1);
  float brx=fminf(ax2,bx2), bry=fminf(ay2,by2);
  float inter=(brx-tlx)*(bry-tly);
  if(!(tlx<brx && tly<bry)) inter=0.0f;
  float iou = inter/((aar+bar)-inter);
  return iou >= NMS_THR;
}

__device__ __forceinline__ u64 rfl64(u64 v){
  u32 lo = (u32)__builtin_amdgcn_readfirstlane((int)(u32)(v & 0xffffffffull));
  u32 hi = (u32)__builtin_amdgcn_readfirstlane((int)(u32)(v>>32));
  return (((u64)hi)<<32) | (u64)lo;
}

// ---------------- decode ----------------
__global__ void k_decode(const float* __restrict__ feat, const float* __restrict__ anchors,
                         float4* __restrict__ obox, float* __restrict__ oobj,
                         float* __restrict__ ocls, float* __restrict__ oscore,
                         u32* __restrict__ okey, int* __restrict__ rank){
  int n = blockIdx.x*256 + threadIdx.x;
  int a = n >> 12;
  int cell = n & 4095;
  int gy = cell >> 6, gx = cell & 63;
  const float* f = feat + a*NCH*4096 + cell;
  float v0=f[0], v1=f[4096], v2=f[8192], v3=f[12288], v4=f[16384], v5=f[20480];
  float aw = anchors[2*a]   * 0.125f;
  float ah = anchors[2*a+1] * 0.125f;
  float px = (sigmf(v0) + (float)gx) * 8.0f;
  float py = (sigmf(v1) + (float)gy) * 8.0f;
  float pw = (expf(v2)*aw) * 8.0f;
  float ph = (expf(v3)*ah) * 8.0f;
  float obj = sigmf(v4), cls = sigmf(v5);
  float4 b;
  b.x = px - pw*0.5f; b.y = py - ph*0.5f;
  b.z = px + pw*0.5f; b.w = py + ph*0.5f;
  float sc = obj*cls;
  obox[n]=b; oobj[n]=obj; ocls[n]=cls; oscore[n]=sc;
  u32 u = __float_as_uint(sc);
  u32 asc = (u & 0x80000000u) ? ~u : (u | 0x80000000u);
  okey[n] = ~asc;            // descending: higher score -> smaller key
  rank[n] = 0;
}

// ---------------- partial rank over a 1024-key slice ----------------
__global__ __launch_bounds__(256) void k_rank_part(const u32* __restrict__ okey,
                                                   int* __restrict__ rank){
  __shared__ u32 tile[1024];
  int n = blockIdx.x*256 + threadIdx.x;
  int t0 = blockIdx.y * 1024;
  u32 my = okey[n];
  for(int k=threadIdx.x;k<1024;k+=256) tile[k]=okey[t0+k];
  __syncthreads();
  int r0=0,r1=0,r2=0,r3=0;
  #pragma unroll 4
  for(int k=0;k<1024;k+=4){
    uint4 kj = *reinterpret_cast<const uint4*>(&tile[k]);
    int j = t0+k;
    r0 += (int)((kj.x<my)||(kj.x==my && (j  )<n));
    r1 += (int)((kj.y<my)||(kj.y==my && (j+1)<n));
    r2 += (int)((kj.z<my)||(kj.z==my && (j+2)<n));
    r3 += (int)((kj.w<my)||(kj.w==my && (j+3)<n));
  }
  atomicAdd(&rank[n], r0+r1+r2+r3);
}

// ---------------- scatter into sorted arrays ----------------
__global__ void k_scatter(const int* __restrict__ rank,
                          const float4* __restrict__ obox,const float* __restrict__ oobj,
                          const float* __restrict__ ocls,const float* __restrict__ oscore,
                          float4* __restrict__ sbox,float* __restrict__ sarea,
                          float* __restrict__ sobj,float* __restrict__ scls,
                          u32* __restrict__ svalid,int* __restrict__ order){
  int n = blockIdx.x*256 + threadIdx.x;
  int r = rank[n];
  float4 b = obox[n];
  sbox[r]=b;
  sarea[r]=(b.z-b.x)*(b.w-b.y);
  sobj[r]=oobj[n]; scls[r]=ocls[n];
  svalid[r] = (oscore[n] >= CONF_THR) ? 1u : 0u;
  order[r]=n;
}

// ---------------- intra-word column masks + valid words ----------------
__global__ __launch_bounds__(256) void k_cmv(const float4* __restrict__ sbox,
                       const float* __restrict__ sarea,const u32* __restrict__ svalid,
                       u64* __restrict__ colmask,u64* __restrict__ validw){
  __shared__ float4 bb[256];
  __shared__ float  ar[256];
  int j = blockIdx.x*256 + threadIdx.x;
  int lane = threadIdx.x & 63;
  float4 b = sbox[j];
  float bar_ = sarea[j];
  bb[threadIdx.x]=b; ar[threadIdx.x]=bar_;
  __syncthreads();
  int base = threadIdx.x & ~63;
  u64 bits=0;
  for(int t=0;t<lane;t++){
    float4 a = bb[base+t];
    if(sup_pair(a.x,a.y,a.z,a.w,ar[base+t], b.x,b.y,b.z,b.w,bar_))
      bits |= (1ull<<(unsigned)t);
  }
  colmask[j]=bits;
  u64 vb = __ballot(svalid[j]!=0u);
  if(lane==0) validw[j>>6]=vb;
}

// ---------------- suppression rows: dense bitmap + sparse (word,bits) records ----------------
__global__ __launch_bounds__(256) void k_rows(const float4* __restrict__ sbox,
                       const float* __restrict__ sarea,
                       u64* __restrict__ rowsD, uint4* __restrict__ sparse){
  int i   = (blockIdx.x*256 + threadIdx.x) >> 6;   // row index = wave id
  int lane = threadIdx.x & 63;
  float4 a = sbox[i];
  float aar = sarea[i];
  int w0 = i >> 6;
  u64 r0=0,r1=0,r2=0;
  for(int w=w0; w<NW; ++w){
    int j = (w<<6) | lane;
    float4 b = sbox[j];
    bool s = (j>i) && sup_pair(a.x,a.y,a.z,a.w,aar, b.x,b.y,b.z,b.w,sarea[j]);
    u64 word = __ballot(s);
    if(lane == (w&63)){
      int sl = w>>6;
      if(sl==0) r0=word; else if(sl==1) r1=word; else r2=word;
    }
  }
  // dense write (fallback for overflow rows); garbage below w0 is never consumed
  u64* rowp = rowsD + (size_t)i*NW;
  if(lane      >= w0) rowp[lane]      = r0;
  if(64+lane   >= w0) rowp[64+lane]   = r1;
  if(128+lane  >= w0) rowp[128+lane]  = r2;
  // sparse build: exclude own word (intra-word handled by colmask)
  int s0 = w0>>6, l0 = w0&63;
  if(s0==0 && lane==l0) r0=0;
  if(s0==1 && lane==l0) r1=0;
  if(s0==2 && lane==l0) r2=0;
  u64 b0=__ballot(r0!=0ull), b1=__ballot(r1!=0ull), b2=__ballot(r2!=0ull);
  int n0=__popcll(b0), n1=__popcll(b1);
  int total = n0+n1+__popcll(b2);
  u64 below = (1ull<<(unsigned)lane)-1ull;
  uint4* sp = sparse + (size_t)i*SPW;
  if(lane==0){
    uint4 h; h.x = (total<=31)?(u32)total:255u; h.y=0;h.z=0;h.w=0;
    sp[0]=h;
  }
  if(total<=31){
    if(r0){ int p=__popcll(b0&below);
      uint4 e; e.x=(u32)lane;     e.y=(u32)r0; e.z=(u32)(r0>>32); e.w=0; sp[1+p]=e; }
    if(r1){ int p=n0+__popcll(b1&below);
      uint4 e; e.x=(u32)(64+lane); e.y=(u32)r1; e.z=(u32)(r1>>32); e.w=0; sp[1+p]=e; }
    if(r2){ int p=n0+n1+__popcll(b2&below);
      uint4 e; e.x=(u32)(128+lane);e.y=(u32)r2; e.z=(u32)(r2>>32); e.w=0; sp[1+p]=e; }
  }
}

// ---------------- single-WG greedy scan: speculative sparse prefetch + LDS mask ----------------
__global__ __launch_bounds__(256) void k_scan2(const uint4* __restrict__ sparse,
                       const u64* __restrict__ colm,const u64* __restrict__ validw_g,
                       const u64* __restrict__ rowsD,u64* __restrict__ keepw){
  __shared__ u32 maskL[2*NW];
  __shared__ u64 valL[NW];
  __shared__ u64 keepshare;
  __shared__ u32 cntL[64];
  __shared__ int ovfcnt;
  __shared__ int ovflist[64];

  int tid = threadIdx.x;
  int lane = tid & 63;
  int slot = tid & 31;          // uint4 slot within a sparse row
  int rbase = tid >> 5;         // rows rbase + 8k held by this thread

  for(int t=tid;t<2*NW;t+=256) maskL[t]=0u;
  for(int t=tid;t<NW;t+=256)   valL[t]=validw_g[t];
  if(tid==0) ovfcnt=0;
  __syncthreads();

  uint4 rA[8], rB[8];
  u64 colA=0, colB=0;
  {
    const uint4* base = sparse;          // word 0 block
    #pragma unroll
    for(int k=0;k<8;k++) rA[k]=base[tid+256*k];
    if(tid<64) colA = colm[tid];
  }

  for(int w=0; w<NW; ++w){
    // speculative prefetch of word w+1 (independent of this word's decision)
    if(w+1<NW){
      const uint4* base = sparse + (size_t)(w+1)*64*SPW;
      #pragma unroll
      for(int k=0;k<8;k++) rB[k]=base[tid+256*k];
      if(tid<64) colB = colm[(w+1)*64+tid];
    }
    // A: greedy decision for word w (wave 0)
    if(tid<64){
      u64 supw = ((u64)maskL[2*w+1]<<32)|(u64)maskL[2*w];
      u64 cand = rfl64(valL[w] & ~supw);
      u64 colv = colA;
      u64 keep64 = 0;
      while(cand){
        unsigned t = (unsigned)__builtin_ctzll(cand);
        keep64 |= (1ull<<t);
        cand &= ~(1ull<<t);
        u64 died = __ballot(((colv>>t)&1ull)!=0ull);
        cand &= ~died;
      }
      if(lane==0){ keepshare=keep64; keepw[w]=keep64; }
    }
    __syncthreads();
    u64 ks = keepshare;
    // B1: publish counts; collect overflow rows (slot-0 threads hold headers)
    if(slot==0){
      #pragma unroll
      for(int k=0;k<8;k++){
        int r = rbase + 8*k;
        u32 c = rA[k].x;
        cntL[r]=c;
        if(c==255u && ((ks>>(unsigned)r)&1ull)){
          int p=atomicAdd(&ovfcnt,1);
          ovflist[p]=w*64+r;
        }
      }
    }
    __syncthreads();
    // B2: apply sparse entries of kept rows
    if(slot!=0){
      u32 e = (u32)(slot-1);
      #pragma unroll
      for(int k=0;k<8;k++){
        int r = rbase + 8*k;
        u32 c = cntL[r];
        if(c!=255u && e<c && ((ks>>(unsigned)r)&1ull)){
          atomicOr(&maskL[2*rA[k].x],   rA[k].y);
          atomicOr(&maskL[2*rA[k].x+1], rA[k].z);
        }
      }
    }
    __syncthreads();
    // C: rare dense fallback for overflow rows
    int oc = ovfcnt;
    if(oc>0){
      if(tid<NW){
        u32 alo=0, ahi=0;
        for(int o=0;o<oc;o++){
          u64 rw = rowsD[(size_t)ovflist[o]*NW + tid];
          alo |= (u32)rw; ahi |= (u32)(rw>>32);
        }
        maskL[2*tid]   |= alo;   // unique owner per word
        maskL[2*tid+1] |= ahi;
      }
      if(tid==64) ovfcnt=0;
      __syncthreads();
    }
    // rotate buffers
    #pragma unroll
    for(int k=0;k<8;k++) rA[k]=rB[k];
    colA=colB;
  }
}

// ---------------- final output ----------------
__global__ void k_final(const int* __restrict__ order,const u64* __restrict__ keepw,
                        const float4* __restrict__ sbox,const float* __restrict__ sobj,
                        const float* __restrict__ scls,float* __restrict__ out){
  int i = blockIdx.x*256 + threadIdx.x;
  int n = order[i];
  u64 kw = keepw[i>>6];
  float kf = ((kw>>(unsigned)(i&63))&1ull) ? 1.0f : 0.0f;
  float4 b = sbox[i];
  float* det = out + (size_t)n*6;
  det[0]=b.x*kf; det[1]=b.y*kf; det[2]=b.z*kf; det[3]=b.w*kf;
  det[4]=sobj[i]*kf; det[5]=scls[i]*kf;
  out[NTOT*6 + n] = kf;
}

extern "C" void kernel_launch(void* const* d_in,const int* in_sizes,int n_in,
                              void* d_out,int out_size,void* d_ws,size_t ws_size,
                              hipStream_t stream){
  const float* feat=(const float*)d_in[0];
  const float* anchors=(const float*)d_in[1];
  float* out=(float*)d_out;

  char* w=(char*)d_ws;
  auto alloc=[&](size_t bytes)->char*{ char* p=w; w += (bytes+255)&~255ull; return p; };
  float4 *obox =(float4*)alloc(NTOT*16);
  float  *oobj =(float*) alloc(NTOT*4);
  float  *ocls =(float*) alloc(NTOT*4);
  float  *oscore=(float*)alloc(NTOT*4);
  u32    *okey =(u32*)   alloc(NTOT*4);
  int    *rank =(int*)   alloc(NTOT*4);
  float4 *sbox =(float4*)alloc(NTOT*16);
  float  *sarea=(float*) alloc(NTOT*4);
  float  *sobj =(float*) alloc(NTOT*4);
  float  *scls =(float*) alloc(NTOT*4);
  u32    *svalid=(u32*)  alloc(NTOT*4);
  int    *order=(int*)   alloc(NTOT*4);
  u64    *colmask=(u64*) alloc(NTOT*8);
  u64    *validw =(u64*) alloc(NW*8);
  u64    *keepw  =(u64*) alloc(NW*8);
  uint4  *sparse =(uint4*)alloc((size_t)NTOT*SPW*16);   // 6 MB
  u64    *rowsD  =(u64*) alloc((size_t)NTOT*NW*8);      // 18.9 MB

  hipLaunchKernelGGL(k_decode, dim3(NTOT/256),dim3(256),0,stream,
                     feat,anchors,obox,oobj,ocls,oscore,okey,rank);
  hipLaunchKernelGGL(k_rank_part, dim3(NTOT/256,12),dim3(256),0,stream, okey,rank);
  hipLaunchKernelGGL(k_scatter, dim3(NTOT/256),dim3(256),0,stream,
                     rank,obox,oobj,ocls,oscore,sbox,sarea,sobj,scls,svalid,order);
  hipLaunchKernelGGL(k_cmv, dim3(NTOT/256),dim3(256),0,stream,
                     sbox,sarea,svalid,colmask,validw);
  hipLaunchKernelGGL(k_rows, dim3(NTOT/4),dim3(256),0,stream, sbox,sarea,rowsD,sparse);
  hipLaunchKernelGGL(k_scan2, dim3(1),dim3(256),0,stream, sparse,colmask,validw,rowsD,keepw);
  hipLaunchKernelGGL(k_final, dim3(NTOT/256),dim3(256),0,stream,
                     order,keepw,sbox,sobj,scls,out);
}

// Round 4
// 755.164 us; speedup vs baseline: 5.3315x; 1.1664x over previous
//
#include <hip/hip_runtime.h>
#include <stdint.h>

#define NTOT   12288
#define NW     192           // NTOT/64 suppression-mask words
#define NCH    6
#define SLOTS  24            // uint4 per row record: slot0 = header, 1..23 = entries
#define BLKU4  (64*SLOTS)    // 1536 uint4 per word-block
#define CONF_THR 0.01f
#define NMS_THR  0.45f

typedef unsigned long long u64;
typedef uint32_t u32;

__device__ __forceinline__ float sigmf(float x){ return 1.0f/(1.0f+expf(-x)); }

// exact reference IoU-suppression test
__device__ __forceinline__ bool sup_pair(float ax1,float ay1,float ax2,float ay2,float aar,
                                         float bx1,float by1,float bx2,float by2,float bar){
  float tlx=fmaxf(ax1,bx1), tly=fmaxf(ay1,by1);
  float brx=fminf(ax2,bx2), bry=fminf(ay2,by2);
  float inter=(brx-tlx)*(bry-tly);
  if(!(tlx<brx && tly<bry)) inter=0.0f;
  float iou = inter/((aar+bar)-inter);
  return iou >= NMS_THR;
}

__device__ __forceinline__ u64 rfl64(u64 v){
  u32 lo = (u32)__builtin_amdgcn_readfirstlane((int)(u32)(v & 0xffffffffull));
  u32 hi = (u32)__builtin_amdgcn_readfirstlane((int)(u32)(v>>32));
  return (((u64)hi)<<32) | (u64)lo;
}

// ---------------- decode ----------------
__global__ void k_decode(const float* __restrict__ feat, const float* __restrict__ anchors,
                         float4* __restrict__ obox, float* __restrict__ oobj,
                         float* __restrict__ ocls, float* __restrict__ oscore,
                         u32* __restrict__ okey, int* __restrict__ rank){
  int n = blockIdx.x*256 + threadIdx.x;
  int a = n >> 12;
  int cell = n & 4095;
  int gy = cell >> 6, gx = cell & 63;
  const float* f = feat + a*NCH*4096 + cell;
  float v0=f[0], v1=f[4096], v2=f[8192], v3=f[12288], v4=f[16384], v5=f[20480];
  float aw = anchors[2*a]   * 0.125f;
  float ah = anchors[2*a+1] * 0.125f;
  float px = (sigmf(v0) + (float)gx) * 8.0f;
  float py = (sigmf(v1) + (float)gy) * 8.0f;
  float pw = (expf(v2)*aw) * 8.0f;
  float ph = (expf(v3)*ah) * 8.0f;
  float obj = sigmf(v4), cls = sigmf(v5);
  float4 b;
  b.x = px - pw*0.5f; b.y = py - ph*0.5f;
  b.z = px + pw*0.5f; b.w = py + ph*0.5f;
  float sc = obj*cls;
  obox[n]=b; oobj[n]=obj; ocls[n]=cls; oscore[n]=sc;
  u32 u = __float_as_uint(sc);
  u32 asc = (u & 0x80000000u) ? ~u : (u | 0x80000000u);
  okey[n] = ~asc;            // descending: higher score -> smaller key
  rank[n] = 0;
}

// ---------------- partial rank over a 1024-key slice ----------------
__global__ __launch_bounds__(256) void k_rank_part(const u32* __restrict__ okey,
                                                   int* __restrict__ rank){
  __shared__ u32 tile[1024];
  int n = blockIdx.x*256 + threadIdx.x;
  int t0 = blockIdx.y * 1024;
  u32 my = okey[n];
  for(int k=threadIdx.x;k<1024;k+=256) tile[k]=okey[t0+k];
  __syncthreads();
  int r0=0,r1=0,r2=0,r3=0;
  #pragma unroll 4
  for(int k=0;k<1024;k+=4){
    uint4 kj = *reinterpret_cast<const uint4*>(&tile[k]);
    int j = t0+k;
    r0 += (int)((kj.x<my)||(kj.x==my && (j  )<n));
    r1 += (int)((kj.y<my)||(kj.y==my && (j+1)<n));
    r2 += (int)((kj.z<my)||(kj.z==my && (j+2)<n));
    r3 += (int)((kj.w<my)||(kj.w==my && (j+3)<n));
  }
  atomicAdd(&rank[n], r0+r1+r2+r3);
}

// ---------------- scatter into sorted arrays ----------------
__global__ void k_scatter(const int* __restrict__ rank,
                          const float4* __restrict__ obox,const float* __restrict__ oobj,
                          const float* __restrict__ ocls,const float* __restrict__ oscore,
                          float4* __restrict__ sbox,float* __restrict__ sarea,
                          float* __restrict__ sobj,float* __restrict__ scls,
                          u32* __restrict__ svalid,int* __restrict__ order){
  int n = blockIdx.x*256 + threadIdx.x;
  int r = rank[n];
  float4 b = obox[n];
  sbox[r]=b;
  sarea[r]=(b.z-b.x)*(b.w-b.y);
  sobj[r]=oobj[n]; scls[r]=ocls[n];
  svalid[r] = (oscore[n] >= CONF_THR) ? 1u : 0u;
  order[r]=n;
}

// ---------------- intra-word column masks (into sparse headers) + valid words ----------------
__global__ __launch_bounds__(256) void k_cmv(const float4* __restrict__ sbox,
                       const float* __restrict__ sarea,const u32* __restrict__ svalid,
                       uint4* __restrict__ sparse,u64* __restrict__ validw){
  __shared__ float4 bb[256];
  __shared__ float  ar[256];
  int j = blockIdx.x*256 + threadIdx.x;
  int lane = threadIdx.x & 63;
  float4 b = sbox[j];
  float bar_ = sarea[j];
  bb[threadIdx.x]=b; ar[threadIdx.x]=bar_;
  __syncthreads();
  int base = threadIdx.x & ~63;
  u64 bits=0;
  for(int t=0;t<lane;t++){
    float4 a = bb[base+t];
    if(sup_pair(a.x,a.y,a.z,a.w,ar[base+t], b.x,b.y,b.z,b.w,bar_))
      bits |= (1ull<<(unsigned)t);
  }
  // header slot of row j: fields y,z = colmask (x written by k_rows; disjoint)
  u32* h = (u32*)(sparse + (size_t)(j>>6)*BLKU4 + (j&63));
  h[1]=(u32)bits; h[2]=(u32)(bits>>32);
  u64 vb = __ballot(svalid[j]!=0u);
  if(lane==0) validw[j>>6]=vb;
}

// ---------------- suppression rows: dense bitmap + sparse slot-major records ----------------
__global__ __launch_bounds__(256) void k_rows(const float4* __restrict__ sbox,
                       const float* __restrict__ sarea,
                       u64* __restrict__ rowsD, uint4* __restrict__ sparse){
  int i   = (blockIdx.x*256 + threadIdx.x) >> 6;   // row index = wave id
  int lane = threadIdx.x & 63;
  float4 a = sbox[i];
  float aar = sarea[i];
  int w0 = i >> 6;
  u64 r0=0,r1=0,r2=0;
  for(int w=w0; w<NW; ++w){
    int j = (w<<6) | lane;
    float4 b = sbox[j];
    bool s = (j>i) && sup_pair(a.x,a.y,a.z,a.w,aar, b.x,b.y,b.z,b.w,sarea[j]);
    u64 word = __ballot(s);
    if(lane == (w&63)){
      int sl = w>>6;
      if(sl==0) r0=word; else if(sl==1) r1=word; else r2=word;
    }
  }
  // dense write (fallback for overflow rows); garbage below w0 is never consumed meaningfully
  u64* rowp = rowsD + (size_t)i*NW;
  if(lane      >= w0) rowp[lane]      = r0;
  if(64+lane   >= w0) rowp[64+lane]   = r1;
  if(128+lane  >= w0) rowp[128+lane]  = r2;
  // sparse build: exclude own word (intra-word handled by header colmask)
  int s0 = w0>>6, l0 = w0&63;
  if(s0==0 && lane==l0) r0=0;
  if(s0==1 && lane==l0) r1=0;
  if(s0==2 && lane==l0) r2=0;
  u64 b0=__ballot(r0!=0ull), b1=__ballot(r1!=0ull), b2=__ballot(r2!=0ull);
  int n0=__popcll(b0), n1=__popcll(b1);
  int total = n0+n1+__popcll(b2);
  u64 below = (1ull<<(unsigned)lane)-1ull;
  uint4* sp4 = sparse + (size_t)(i>>6)*BLKU4;   // word-block of this row
  int il = i & 63;
  if(lane==0) ((u32*)(sp4+il))[0] = (total<=23)?(u32)total:255u;   // header.x = count
  if(total<=23){
    if(r0){ int p=__popcll(b0&below);
      sp4[(1+p)*64+il]=make_uint4((u32)lane,     (u32)r0,(u32)(r0>>32),0u); }
    if(r1){ int p=n0+__popcll(b1&below);
      sp4[(1+p)*64+il]=make_uint4((u32)(64+lane),(u32)r1,(u32)(r1>>32),0u); }
    if(r2){ int p=n0+n1+__popcll(b2&below);
      sp4[(1+p)*64+il]=make_uint4((u32)(128+lane),(u32)r2,(u32)(r2>>32),0u); }
  }
}

// ---------------- single-WG greedy scan: LDS double-buffered sparse pipeline ----------------
__global__ __launch_bounds__(256) void k_scan3(const uint4* __restrict__ sparse,
                       const u64* __restrict__ validw_g,
                       const u64* __restrict__ rowsD, u64* __restrict__ keepw){
  __shared__ uint4 spbuf[2][BLKU4];     // 2 x 24 KB, slot-major [slot][row]
  __shared__ u32 maskLo[NW], maskHi[NW];
  __shared__ u64 valL[NW], keepL_[NW];
  __shared__ u64 sh_keep, sh_ovf;

  int tid=threadIdx.x, lane=tid&63, wv=tid>>6;
  for(int t=tid;t<NW;t+=256){ maskLo[t]=0u; maskHi[t]=0u; valL[t]=validw_g[t]; }
  __syncthreads();
  // prologue: stage word-0 block synchronously
  {
    const uint4* g = sparse;
    uint4 a0=g[tid],a1=g[tid+256],a2=g[tid+512],a3=g[tid+768],a4=g[tid+1024],a5=g[tid+1280];
    spbuf[0][tid]=a0; spbuf[0][tid+256]=a1; spbuf[0][tid+512]=a2;
    spbuf[0][tid+768]=a3; spbuf[0][tid+1024]=a4; spbuf[0][tid+1280]=a5;
  }
  __syncthreads();

  for(int w=0; w<NW; ++w){
    int cur = w&1, nxt = cur^1;
    bool havenext = (w+1<NW);
    // issue next block's loads early (named regs -> no spill; consumed at bottom)
    uint4 g0,g1,g2,g3,g4,g5;
    if(havenext){
      const uint4* g = sparse + (size_t)(w+1)*BLKU4;
      g0=g[tid]; g1=g[tid+256]; g2=g[tid+512]; g3=g[tid+768]; g4=g[tid+1024]; g5=g[tid+1280];
    }
    // decision for word w (wave 0 only)
    if(tid<64){
      uint4 hdr = spbuf[cur][lane];                 // stride-16B, conflict-free
      u64 colv = (((u64)hdr.z)<<32) | (u64)hdr.y;
      u64 supw = (((u64)maskHi[w])<<32) | (u64)maskLo[w];
      u64 cand = rfl64(valL[w] & ~supw);
      u64 keep64 = 0;
      while(cand){
        unsigned t = (unsigned)__builtin_ctzll(cand);
        keep64 |= (1ull<<t);
        cand &= ~(1ull<<t);
        u64 died = __ballot(((colv>>t)&1ull)!=0ull);
        cand &= ~died;
      }
      u64 ovf = __ballot((((keep64>>lane)&1ull)!=0ull) && hdr.x==255u);
      if(lane==0){ sh_keep=keep64; sh_ovf=ovf; keepL_[w]=keep64; }
    }
    __syncthreads();
    u64 ks = sh_keep, ov = sh_ovf;
    // apply sparse entries of kept rows: wave wv handles entry slots e = wv*6+q
    {
      u32 cnt = spbuf[cur][lane].x;
      bool kept = ((ks>>(unsigned)lane)&1ull)!=0ull;
      if(kept && cnt!=255u){
        #pragma unroll
        for(int q=0;q<6;q++){
          int e = wv*6+q;
          if(e<23 && (u32)e<cnt){
            uint4 en = spbuf[cur][(1+e)*64 + lane];
            atomicOr(&maskLo[en.x], en.y);
            atomicOr(&maskHi[en.x], en.z);
          }
        }
      }
    }
    // dense fallback for overflow kept rows (rare)
    if(ov){
      if(tid<NW && tid>w){
        u32 alo=0, ahi=0;
        u64 t_ov=ov;
        while(t_ov){
          int o=__builtin_ctzll(t_ov); t_ov &= t_ov-1ull;
          u64 d = rowsD[(size_t)(w*64+o)*NW + tid];
          alo |= (u32)d; ahi |= (u32)(d>>32);
        }
        if(alo) atomicOr(&maskLo[tid], alo);
        if(ahi) atomicOr(&maskHi[tid], ahi);
      }
    }
    __syncthreads();
    // write staged block into the other LDS buffer (vmcnt hidden under decision+apply)
    if(havenext){
      spbuf[nxt][tid]=g0; spbuf[nxt][tid+256]=g1; spbuf[nxt][tid+512]=g2;
      spbuf[nxt][tid+768]=g3; spbuf[nxt][tid+1024]=g4; spbuf[nxt][tid+1280]=g5;
    }
    __syncthreads();
  }
  for(int t=tid;t<NW;t+=256) keepw[t]=keepL_[t];
}

// ---------------- final output ----------------
__global__ void k_final(const int* __restrict__ order,const u64* __restrict__ keepw,
                        const float4* __restrict__ sbox,const float* __restrict__ sobj,
                        const float* __restrict__ scls,float* __restrict__ out){
  int i = blockIdx.x*256 + threadIdx.x;
  int n = order[i];
  u64 kw = keepw[i>>6];
  float kf = ((kw>>(unsigned)(i&63))&1ull) ? 1.0f : 0.0f;
  float4 b = sbox[i];
  float* det = out + (size_t)n*6;
  det[0]=b.x*kf; det[1]=b.y*kf; det[2]=b.z*kf; det[3]=b.w*kf;
  det[4]=sobj[i]*kf; det[5]=scls[i]*kf;
  out[NTOT*6 + n] = kf;
}

extern "C" void kernel_launch(void* const* d_in,const int* in_sizes,int n_in,
                              void* d_out,int out_size,void* d_ws,size_t ws_size,
                              hipStream_t stream){
  const float* feat=(const float*)d_in[0];
  const float* anchors=(const float*)d_in[1];
  float* out=(float*)d_out;

  char* w=(char*)d_ws;
  auto alloc=[&](size_t bytes)->char*{ char* p=w; w += (bytes+255)&~255ull; return p; };
  float4 *obox =(float4*)alloc(NTOT*16);
  float  *oobj =(float*) alloc(NTOT*4);
  float  *ocls =(float*) alloc(NTOT*4);
  float  *oscore=(float*)alloc(NTOT*4);
  u32    *okey =(u32*)   alloc(NTOT*4);
  int    *rank =(int*)   alloc(NTOT*4);
  float4 *sbox =(float4*)alloc(NTOT*16);
  float  *sarea=(float*) alloc(NTOT*4);
  float  *sobj =(float*) alloc(NTOT*4);
  float  *scls =(float*) alloc(NTOT*4);
  u32    *svalid=(u32*)  alloc(NTOT*4);
  int    *order=(int*)   alloc(NTOT*4);
  u64    *validw =(u64*) alloc(NW*8);
  u64    *keepw  =(u64*) alloc(NW*8);
  uint4  *sparse =(uint4*)alloc((size_t)NW*BLKU4*16);   // 4.7 MB slot-major blocks
  u64    *rowsD  =(u64*) alloc((size_t)NTOT*NW*8);      // 18.9 MB dense fallback

  hipLaunchKernelGGL(k_decode, dim3(NTOT/256),dim3(256),0,stream,
                     feat,anchors,obox,oobj,ocls,oscore,okey,rank);
  hipLaunchKernelGGL(k_rank_part, dim3(NTOT/256,12),dim3(256),0,stream, okey,rank);
  hipLaunchKernelGGL(k_scatter, dim3(NTOT/256),dim3(256),0,stream,
                     rank,obox,oobj,ocls,oscore,sbox,sarea,sobj,scls,svalid,order);
  hipLaunchKernelGGL(k_cmv, dim3(NTOT/256),dim3(256),0,stream,
                     sbox,sarea,svalid,sparse,validw);
  hipLaunchKernelGGL(k_rows, dim3(NTOT/4),dim3(256),0,stream, sbox,sarea,rowsD,sparse);
  hipLaunchKernelGGL(k_scan3, dim3(1),dim3(256),0,stream, sparse,validw,rowsD,keepw);
  hipLaunchKernelGGL(k_final, dim3(NTOT/256),dim3(256),0,stream,
                     order,keepw,sbox,sobj,scls,out);
}

// Round 5
// 736.875 us; speedup vs baseline: 5.4638x; 1.0248x over previous
//
#include <hip/hip_runtime.h>
#include <stdint.h>

#define NTOT   12288
#define NW     192           // NTOT/64 suppression-mask words
#define NCH    6
#define SLOTS  12            // uint4 per row record: slot0 = header, 1..11 = entries
#define BLKU4  (64*SLOTS)    // 768 uint4 per word-block (12 KB)
#define CONF_THR 0.01f
#define NMS_THR  0.45f

typedef unsigned long long u64;
typedef uint32_t u32;

__device__ __forceinline__ float sigmf(float x){ return 1.0f/(1.0f+expf(-x)); }

// exact reference IoU-suppression test
__device__ __forceinline__ bool sup_pair(float ax1,float ay1,float ax2,float ay2,float aar,
                                         float bx1,float by1,float bx2,float by2,float bar){
  float tlx=fmaxf(ax1,bx1), tly=fmaxf(ay1,by1);
  float brx=fminf(ax2,bx2), bry=fminf(ay2,by2);
  float inter=(brx-tlx)*(bry-tly);
  if(!(tlx<brx && tly<bry)) inter=0.0f;
  float iou = inter/((aar+bar)-inter);
  return iou >= NMS_THR;
}

__device__ __forceinline__ u64 rfl64(u64 v){
  u32 lo = (u32)__builtin_amdgcn_readfirstlane((int)(u32)(v & 0xffffffffull));
  u32 hi = (u32)__builtin_amdgcn_readfirstlane((int)(u32)(v>>32));
  return (((u64)hi)<<32) | (u64)lo;
}

// ---------------- decode ----------------
__global__ void k_decode(const float* __restrict__ feat, const float* __restrict__ anchors,
                         float4* __restrict__ obox, float* __restrict__ oobj,
                         float* __restrict__ ocls, float* __restrict__ oscore,
                         u32* __restrict__ okey, int* __restrict__ rank){
  int n = blockIdx.x*256 + threadIdx.x;
  int a = n >> 12;
  int cell = n & 4095;
  int gy = cell >> 6, gx = cell & 63;
  const float* f = feat + a*NCH*4096 + cell;
  float v0=f[0], v1=f[4096], v2=f[8192], v3=f[12288], v4=f[16384], v5=f[20480];
  float aw = anchors[2*a]   * 0.125f;
  float ah = anchors[2*a+1] * 0.125f;
  float px = (sigmf(v0) + (float)gx) * 8.0f;
  float py = (sigmf(v1) + (float)gy) * 8.0f;
  float pw = (expf(v2)*aw) * 8.0f;
  float ph = (expf(v3)*ah) * 8.0f;
  float obj = sigmf(v4), cls = sigmf(v5);
  float4 b;
  b.x = px - pw*0.5f; b.y = py - ph*0.5f;
  b.z = px + pw*0.5f; b.w = py + ph*0.5f;
  float sc = obj*cls;
  obox[n]=b; oobj[n]=obj; ocls[n]=cls; oscore[n]=sc;
  u32 u = __float_as_uint(sc);
  u32 asc = (u & 0x80000000u) ? ~u : (u | 0x80000000u);
  okey[n] = ~asc;            // descending: higher score -> smaller key
  rank[n] = 0;
}

// ---------------- partial rank over a 1024-key slice ----------------
__global__ __launch_bounds__(256) void k_rank_part(const u32* __restrict__ okey,
                                                   int* __restrict__ rank){
  __shared__ u32 tile[1024];
  int n = blockIdx.x*256 + threadIdx.x;
  int t0 = blockIdx.y * 1024;
  u32 my = okey[n];
  for(int k=threadIdx.x;k<1024;k+=256) tile[k]=okey[t0+k];
  __syncthreads();
  int r0=0,r1=0,r2=0,r3=0;
  #pragma unroll 4
  for(int k=0;k<1024;k+=4){
    uint4 kj = *reinterpret_cast<const uint4*>(&tile[k]);
    int j = t0+k;
    r0 += (int)((kj.x<my)||(kj.x==my && (j  )<n));
    r1 += (int)((kj.y<my)||(kj.y==my && (j+1)<n));
    r2 += (int)((kj.z<my)||(kj.z==my && (j+2)<n));
    r3 += (int)((kj.w<my)||(kj.w==my && (j+3)<n));
  }
  atomicAdd(&rank[n], r0+r1+r2+r3);
}

// ---------------- scatter into sorted arrays ----------------
__global__ void k_scatter(const int* __restrict__ rank,
                          const float4* __restrict__ obox,const float* __restrict__ oobj,
                          const float* __restrict__ ocls,const float* __restrict__ oscore,
                          float4* __restrict__ sbox,float* __restrict__ sarea,
                          float* __restrict__ sobj,float* __restrict__ scls,
                          u32* __restrict__ svalid,int* __restrict__ order){
  int n = blockIdx.x*256 + threadIdx.x;
  int r = rank[n];
  float4 b = obox[n];
  sbox[r]=b;
  sarea[r]=(b.z-b.x)*(b.w-b.y);
  sobj[r]=oobj[n]; scls[r]=ocls[n];
  svalid[r] = (oscore[n] >= CONF_THR) ? 1u : 0u;
  order[r]=n;
}

// ---------------- intra-word column masks (into sparse headers) + valid words ----------------
__global__ __launch_bounds__(256) void k_cmv(const float4* __restrict__ sbox,
                       const float* __restrict__ sarea,const u32* __restrict__ svalid,
                       uint4* __restrict__ sparse,u64* __restrict__ validw){
  __shared__ float4 bb[256];
  __shared__ float  ar[256];
  int j = blockIdx.x*256 + threadIdx.x;
  int lane = threadIdx.x & 63;
  float4 b = sbox[j];
  float bar_ = sarea[j];
  bb[threadIdx.x]=b; ar[threadIdx.x]=bar_;
  __syncthreads();
  int base = threadIdx.x & ~63;
  u64 bits=0;
  for(int t=0;t<lane;t++){
    float4 a = bb[base+t];
    if(sup_pair(a.x,a.y,a.z,a.w,ar[base+t], b.x,b.y,b.z,b.w,bar_))
      bits |= (1ull<<(unsigned)t);
  }
  // header slot of row j: fields y,z = colmask (x written by k_rows; disjoint)
  u32* h = (u32*)(sparse + (size_t)(j>>6)*BLKU4 + (j&63));
  h[1]=(u32)bits; h[2]=(u32)(bits>>32);
  u64 vb = __ballot(svalid[j]!=0u);
  if(lane==0) validw[j>>6]=vb;
}

// ---------------- suppression rows: dense bitmap + sparse slot-major records ----------------
__global__ __launch_bounds__(256) void k_rows(const float4* __restrict__ sbox,
                       const float* __restrict__ sarea,
                       u64* __restrict__ rowsD, uint4* __restrict__ sparse){
  int i   = (blockIdx.x*256 + threadIdx.x) >> 6;   // row index = wave id
  int lane = threadIdx.x & 63;
  float4 a = sbox[i];
  float aar = sarea[i];
  int w0 = i >> 6;
  u64 r0=0,r1=0,r2=0;
  for(int w=w0; w<NW; ++w){
    int j = (w<<6) | lane;
    float4 b = sbox[j];
    bool s = (j>i) && sup_pair(a.x,a.y,a.z,a.w,aar, b.x,b.y,b.z,b.w,sarea[j]);
    u64 word = __ballot(s);
    if(lane == (w&63)){
      int sl = w>>6;
      if(sl==0) r0=word; else if(sl==1) r1=word; else r2=word;
    }
  }
  // dense write (fallback for overflow rows); garbage below w0 is never consumed meaningfully
  u64* rowp = rowsD + (size_t)i*NW;
  if(lane      >= w0) rowp[lane]      = r0;
  if(64+lane   >= w0) rowp[64+lane]   = r1;
  if(128+lane  >= w0) rowp[128+lane]  = r2;
  // sparse build: exclude own word (intra-word handled by header colmask)
  int s0 = w0>>6, l0 = w0&63;
  if(s0==0 && lane==l0) r0=0;
  if(s0==1 && lane==l0) r1=0;
  if(s0==2 && lane==l0) r2=0;
  u64 b0=__ballot(r0!=0ull), b1=__ballot(r1!=0ull), b2=__ballot(r2!=0ull);
  int n0=__popcll(b0), n1=__popcll(b1);
  int total = n0+n1+__popcll(b2);
  u64 below = (1ull<<(unsigned)lane)-1ull;
  uint4* sp4 = sparse + (size_t)(i>>6)*BLKU4;   // word-block of this row
  int il = i & 63;
  if(lane==0) ((u32*)(sp4+il))[0] = (total<=11)?(u32)total:255u;   // header.x = count
  if(total<=11){
    if(r0){ int p=__popcll(b0&below);
      sp4[(1+p)*64+il]=make_uint4((u32)lane,     (u32)r0,(u32)(r0>>32),0u); }
    if(r1){ int p=n0+__popcll(b1&below);
      sp4[(1+p)*64+il]=make_uint4((u32)(64+lane),(u32)r1,(u32)(r1>>32),0u); }
    if(r2){ int p=n0+n1+__popcll(b2&below);
      sp4[(1+p)*64+il]=make_uint4((u32)(128+lane),(u32)r2,(u32)(r2>>32),0u); }
  }
}

// ---------------- single-WAVE greedy scan: register-resident, barrier-free ----------------
__global__ __launch_bounds__(64) void k_scan4(const uint4* __restrict__ sparse,
                       const u64* __restrict__ validw_g,
                       const u64* __restrict__ rowsD, u64* __restrict__ keepw){
  __shared__ u64 maskL[NW];
  __shared__ u64 valL[NW];
  int lane = threadIdx.x;
  #pragma unroll
  for(int t=0;t<3;t++){ maskL[t*64+lane]=0ull; valL[t*64+lane]=validw_g[t*64+lane]; }

#define DECLBUF(P) uint4 P##0,P##1,P##2,P##3,P##4,P##5,P##6,P##7,P##8,P##9,P##10,P##11;
  DECLBUF(A) DECLBUF(B) DECLBUF(C)

#define STAGE(P, wblk) do{ \
    int wc_ = (wblk) < NW ? (wblk) : (NW-1); \
    const uint4* g_ = sparse + (size_t)wc_*BLKU4 + lane; \
    P##0=g_[0];   P##1=g_[64];  P##2=g_[128]; P##3=g_[192]; \
    P##4=g_[256]; P##5=g_[320]; P##6=g_[384]; P##7=g_[448]; \
    P##8=g_[512]; P##9=g_[576]; P##10=g_[640];P##11=g_[704]; }while(0)

#define APPLY(E, S) if(cnt_>= (u32)(S)){ atomicOr(&maskL[(E).x], (((u64)(E).z)<<32)|(u64)(E).y); }

#define PROCESS(P, wexp) do{ \
    int w_ = (wexp); \
    uint4 hdr_ = P##0; \
    u32 cnt_ = hdr_.x; \
    u64 colv_ = (((u64)hdr_.z)<<32)|(u64)hdr_.y; \
    u64 cand_ = rfl64(valL[w_] & ~maskL[w_]); \
    u64 keep64_ = 0; \
    while(cand_){ \
      unsigned t_ = (unsigned)__builtin_ctzll(cand_); \
      keep64_ |= (1ull<<t_); \
      cand_ &= ~(1ull<<t_); \
      u64 died_ = __ballot(((colv_>>t_)&1ull)!=0ull); \
      cand_ &= ~died_; \
    } \
    if(lane==0) keepw[w_]=keep64_; \
    bool kept_ = ((keep64_>>(unsigned)lane)&1ull)!=0ull; \
    if(kept_ && cnt_!=255u){ \
      APPLY(P##1,1)  APPLY(P##2,2)  APPLY(P##3,3)  APPLY(P##4,4) \
      APPLY(P##5,5)  APPLY(P##6,6)  APPLY(P##7,7)  APPLY(P##8,8) \
      APPLY(P##9,9)  APPLY(P##10,10) APPLY(P##11,11) \
    } \
    u64 ovfm_ = __ballot(kept_ && cnt_==255u); \
    while(ovfm_){ \
      int o_ = __builtin_ctzll(ovfm_); ovfm_ &= ovfm_-1ull; \
      const u64* dr_ = rowsD + (size_t)(w_*64+o_)*NW; \
      u64 d0_=dr_[lane], d1_=dr_[64+lane], d2_=dr_[128+lane]; \
      atomicOr(&maskL[lane],     d0_); \
      atomicOr(&maskL[64+lane],  d1_); \
      atomicOr(&maskL[128+lane], d2_); \
    } \
  }while(0)

  STAGE(A, 0);
  STAGE(B, 1);
  for(int w=0; w<NW; w+=3){
    STAGE(C, w+2);  PROCESS(A, w);
    STAGE(A, w+3);  PROCESS(B, w+1);
    STAGE(B, w+4);  PROCESS(C, w+2);
  }
}

// ---------------- final output ----------------
__global__ void k_final(const int* __restrict__ order,const u64* __restrict__ keepw,
                        const float4* __restrict__ sbox,const float* __restrict__ sobj,
                        const float* __restrict__ scls,float* __restrict__ out){
  int i = blockIdx.x*256 + threadIdx.x;
  int n = order[i];
  u64 kw = keepw[i>>6];
  float kf = ((kw>>(unsigned)(i&63))&1ull) ? 1.0f : 0.0f;
  float4 b = sbox[i];
  float* det = out + (size_t)n*6;
  det[0]=b.x*kf; det[1]=b.y*kf; det[2]=b.z*kf; det[3]=b.w*kf;
  det[4]=sobj[i]*kf; det[5]=scls[i]*kf;
  out[NTOT*6 + n] = kf;
}

extern "C" void kernel_launch(void* const* d_in,const int* in_sizes,int n_in,
                              void* d_out,int out_size,void* d_ws,size_t ws_size,
                              hipStream_t stream){
  const float* feat=(const float*)d_in[0];
  const float* anchors=(const float*)d_in[1];
  float* out=(float*)d_out;

  char* w=(char*)d_ws;
  auto alloc=[&](size_t bytes)->char*{ char* p=w; w += (bytes+255)&~255ull; return p; };
  float4 *obox =(float4*)alloc(NTOT*16);
  float  *oobj =(float*) alloc(NTOT*4);
  float  *ocls =(float*) alloc(NTOT*4);
  float  *oscore=(float*)alloc(NTOT*4);
  u32    *okey =(u32*)   alloc(NTOT*4);
  int    *rank =(int*)   alloc(NTOT*4);
  float4 *sbox =(float4*)alloc(NTOT*16);
  float  *sarea=(float*) alloc(NTOT*4);
  float  *sobj =(float*) alloc(NTOT*4);
  float  *scls =(float*) alloc(NTOT*4);
  u32    *svalid=(u32*)  alloc(NTOT*4);
  int    *order=(int*)   alloc(NTOT*4);
  u64    *validw =(u64*) alloc(NW*8);
  u64    *keepw  =(u64*) alloc(NW*8);
  uint4  *sparse =(uint4*)alloc((size_t)NW*BLKU4*16);   // 2.36 MB slot-major blocks
  u64    *rowsD  =(u64*) alloc((size_t)NTOT*NW*8);      // 18.9 MB dense fallback

  hipLaunchKernelGGL(k_decode, dim3(NTOT/256),dim3(256),0,stream,
                     feat,anchors,obox,oobj,ocls,oscore,okey,rank);
  hipLaunchKernelGGL(k_rank_part, dim3(NTOT/256,12),dim3(256),0,stream, okey,rank);
  hipLaunchKernelGGL(k_scatter, dim3(NTOT/256),dim3(256),0,stream,
                     rank,obox,oobj,ocls,oscore,sbox,sarea,sobj,scls,svalid,order);
  hipLaunchKernelGGL(k_cmv, dim3(NTOT/256),dim3(256),0,stream,
                     sbox,sarea,svalid,sparse,validw);
  hipLaunchKernelGGL(k_rows, dim3(NTOT/4),dim3(256),0,stream, sbox,sarea,rowsD,sparse);
  hipLaunchKernelGGL(k_scan4, dim3(1),dim3(64),0,stream, sparse,validw,rowsD,keepw);
  hipLaunchKernelGGL(k_final, dim3(NTOT/256),dim3(256),0,stream,
                     order,keepw,sbox,sobj,scls,out);
}